// Round 1
// baseline (137.481 us; speedup 1.0000x reference)
//
#include <hip/hip_runtime.h>
#include <math.h>

#define DIM 1024
#define NQ 10
#define NL 4
#define SEQ 512
#define NROWS 4096
#define PRED 96

typedef unsigned short ushort_t;
typedef unsigned int uint_t;
using half8   = __attribute__((ext_vector_type(8))) _Float16;
using float4v = __attribute__((ext_vector_type(4))) float;

__device__ inline ushort_t f2h(float f) { _Float16 h = (_Float16)f; return *(ushort_t*)&h; }
__device__ inline uint_t pkh(float a, float b) {
    _Float16 ha = (_Float16)a, hb = (_Float16)b;   // RTE v_cvt_f16_f32
    return (uint_t)(*(ushort_t*)&ha) | ((uint_t)(*(ushort_t*)&hb) << 16);
}

// ---------------------------------------------------------------------------
// Kernel 1 (REWRITTEN): barrier-free register-resident circuit.
// One wave per column j of [W_in | b_in]. Lane l owns 16 states s = l*16+r
// as float2[16] in VGPRs.
//   wire w (state bit 9-w):
//     w in 0..5  -> lane bit (5-w): shfl_xor exchange, coeff select by bit
//     w in 6..9  -> reg-index bit (9-w): in-register complex butterfly
//   layer perm: precomputed u16 table (GF(2) XOR cascade), gather through a
//   wave-PRIVATE LDS scratch; only s_waitcnt lgkmcnt(0), no __syncthreads.
// Single __syncthreads at start (gates + perm tables).
// ---------------------------------------------------------------------------
#define CIRC_WAVES 8

__global__ __launch_bounds__(512)
void circuit_reg_kernel(const float* __restrict__ Wi, const float* __restrict__ b_in,
                        const float* __restrict__ qw,
                        ushort_t* __restrict__ Crt_r, ushort_t* __restrict__ Crt_i,
                        float* __restrict__ dr, float* __restrict__ di)
{
    __shared__ float gm[NL * NQ][8];            // 1.25 KB
    __shared__ ushort_t permtab[NL][DIM];       // 8 KB
    __shared__ float ps[CIRC_WAVES][DIM];       // 32 KB, wave-private slices

    const int tid = threadIdx.x;

    if (tid < NL * NQ) {
        float phi = qw[tid * 3 + 0], theta = qw[tid * 3 + 1], omega = qw[tid * 3 + 2];
        float ch = cosf(theta * 0.5f), sh = sinf(theta * 0.5f);
        float a = 0.5f * (phi + omega), b = 0.5f * (phi - omega);
        float ca = cosf(a), sa = sinf(a);
        float cb = cosf(b), sb = sinf(b);
        gm[tid][0] =  ch * ca;  gm[tid][1] = -ch * sa;   // m00
        gm[tid][2] = -sh * cb;  gm[tid][3] = -sh * sb;   // m01
        gm[tid][4] =  sh * cb;  gm[tid][5] = -sh * sb;   // m10
        gm[tid][6] =  ch * ca;  gm[tid][7] =  ch * sa;   // m11
    }

    // perm tables: new[i] = old[comp_l(i)], comp_l = g0(g1(...g9(i))) XOR cascade
    for (int l = 0; l < NL; ++l) {
        int r = l % (NQ - 1) + 1;
        int p0 = tid, p1 = tid + 512;
#pragma unroll
        for (int c = 9; c >= 0; --c) {
            int t = (c + r) % NQ;
            p0 ^= ((p0 >> (9 - c)) & 1) << (9 - t);
            p1 ^= ((p1 >> (9 - c)) & 1) << (9 - t);
        }
        permtab[l][tid]       = (ushort_t)p0;
        permtab[l][tid + 512] = (ushort_t)p1;
    }
    __syncthreads();   // the ONLY block barrier

    const int lane = tid & 63, wv = tid >> 6;
    const int j = blockIdx.x * CIRC_WAVES + wv;
    if (j > SEQ) return;                       // dead waves only in last block

    const int sbase = lane * 16;
    float2 st[16];
    if (j < SEQ) {
#pragma unroll
        for (int r2 = 0; r2 < 16; ++r2)
            st[r2] = make_float2(Wi[(size_t)(sbase + r2) * SEQ + j], 0.f);
    } else {
#pragma unroll
        for (int r2 = 0; r2 < 16; ++r2)
            st[r2] = make_float2(b_in[sbase + r2] + 1e-6f, 0.f);
    }

    float* Pw = ps[wv];

    for (int l = 0; l < NL; ++l) {
        // wires 0..5: state bit 9-w = lane bit 5-w -> shfl exchange
#pragma unroll
        for (int w = 0; w < 6; ++w) {
            const float* m = gm[l * NQ + w];
            const int lb = 5 - w;
            const int hi = (lane >> lb) & 1;
            // own-coeff cA, partner-coeff cB:
            //   bit==0: new0 = m00*own + m01*partner
            //   bit==1: new1 = m11*own + m10*partner
            float cAr = hi ? m[6] : m[0];
            float cAi = hi ? m[7] : m[1];
            float cBr = hi ? m[4] : m[2];
            float cBi = hi ? m[5] : m[3];
            const int mask = 1 << lb;
#pragma unroll
            for (int r2 = 0; r2 < 16; ++r2) {
                float pr = __shfl_xor(st[r2].x, mask, 64);
                float pi = __shfl_xor(st[r2].y, mask, 64);
                float nr = cAr * st[r2].x - cAi * st[r2].y + cBr * pr - cBi * pi;
                float ni = cAr * st[r2].y + cAi * st[r2].x + cBr * pi + cBi * pr;
                st[r2] = make_float2(nr, ni);
            }
        }
        // wires 6..9: state bit 9-w = reg-index bit -> in-register butterfly
#pragma unroll
        for (int w = 6; w < 10; ++w) {
            const float* m = gm[l * NQ + w];
            float m00r = m[0], m00i = m[1], m01r = m[2], m01i = m[3];
            float m10r = m[4], m10i = m[5], m11r = m[6], m11i = m[7];
            const int db = 1 << (9 - w);
#pragma unroll
            for (int r0 = 0; r0 < 16; ++r0) {
                if (r0 & db) continue;
                const int r1 = r0 | db;
                float2 a0 = st[r0], a1 = st[r1];
                st[r0].x = m00r * a0.x - m00i * a0.y + m01r * a1.x - m01i * a1.y;
                st[r0].y = m00r * a0.y + m00i * a0.x + m01r * a1.y + m01i * a1.x;
                st[r1].x = m10r * a0.x - m10i * a0.y + m11r * a1.x - m11i * a1.y;
                st[r1].y = m10r * a0.y + m10i * a0.x + m11r * a1.y + m11i * a1.x;
            }
        }
        // layer permutation through wave-private LDS (real pass, then imag).
        // lgkmcnt(0) after ds_writes makes them visible to all lanes of this
        // wave; the middle lgkmcnt(0) orders read-data-return before the
        // buffer is overwritten (conservative WAR fence).
        const ushort_t* pt = permtab[l];
        float tmpr[16];
#pragma unroll
        for (int r2 = 0; r2 < 16; ++r2) Pw[sbase + r2] = st[r2].x;
        asm volatile("s_waitcnt lgkmcnt(0)" ::: "memory");
#pragma unroll
        for (int r2 = 0; r2 < 16; ++r2) tmpr[r2] = Pw[pt[sbase + r2]];
        asm volatile("s_waitcnt lgkmcnt(0)" ::: "memory");
#pragma unroll
        for (int r2 = 0; r2 < 16; ++r2) Pw[sbase + r2] = st[r2].y;
        asm volatile("s_waitcnt lgkmcnt(0)" ::: "memory");
#pragma unroll
        for (int r2 = 0; r2 < 16; ++r2) {
            float iy = Pw[pt[sbase + r2]];
            st[r2] = make_float2(tmpr[r2], iy);
        }
    }

    if (j < SEQ) {
#pragma unroll
        for (int r2 = 0; r2 < 16; ++r2) {
            Crt_r[(size_t)(sbase + r2) * SEQ + j] = f2h(st[r2].x);
            Crt_i[(size_t)(sbase + r2) * SEQ + j] = f2h(st[r2].y);
        }
    } else {
#pragma unroll
        for (int r2 = 0; r2 < 16; ++r2) {
            dr[sbase + r2] = st[r2].x;
            di[sbase + r2] = st[r2].y;
        }
    }
}

// ---------------------------------------------------------------------------
// Kernel 2: fused f16-MFMA GEMM + probs + signed partials.
// Same verified 128x64 body; ONLY change: A-staging now reads x in fp32 and
// converts with the same RTE pkh in-register (bitwise-identical A halves to
// the old convert_x path). convert_x kernel is removed.
// ---------------------------------------------------------------------------
#define GBM 128
#define GBNC 64
#define GBK 32
#define LDA 40   // half stride for LDS tiles
#define LDP 65   // float stride for probs tile

__global__ __launch_bounds__(256)
void gemm_fused_kernel(const float* __restrict__ x,
                       const ushort_t* __restrict__ Crt_r, const ushort_t* __restrict__ Crt_i,
                       const float* __restrict__ dr, const float* __restrict__ di,
                       float* __restrict__ part)
{
    __shared__ __align__(16) char lds[GBM * LDP * 4];  // 33280 B (probs tile is max)
    ushort_t* Ash = (ushort_t*)lds;            // 128*40 halves = 10240 B
    ushort_t* Bsr = Ash + GBM * LDA;           // 64*40 = 5120 B
    ushort_t* Bsi = Bsr + GBNC * LDA;          // 64*40 = 5120 B
    float*    Ps  = (float*)lds;               // reused after K-loop
    __shared__ float drs[GBNC], dis[GBNC];

    const int tid = threadIdx.x;
    const int bm = blockIdx.x, bn = blockIdx.y;
    const int lane = tid & 63, wv = tid >> 6;
    const int n0 = bn * GBNC;

    if (tid < GBNC) { drs[tid] = dr[n0 + tid]; dis[tid] = di[n0 + tid]; }

    float4v accr[2][4], acci[2][4];
#pragma unroll
    for (int a = 0; a < 2; ++a)
#pragma unroll
        for (int b = 0; b < 4; ++b) { accr[a][b] = (float4v)0.f; acci[a][b] = (float4v)0.f; }

    // A staging: thread -> row sr (0..127), k offset ko (0 or 16); 16 floats -> 16 halves
    const int sr = tid >> 1, ko = (tid & 1) * 16;
    const float* xa = x + (size_t)(bm * GBM + sr) * SEQ + ko;
    // B staging: threads 0-127 real, 128-255 imag; 16 halves each
    const int bsel = tid >> 7;
    const int nr = (tid & 127) >> 1;
    const int bko = (tid & 1) * 16;
    const ushort_t* bsrc = (bsel ? Crt_i : Crt_r) + (size_t)(n0 + nr) * SEQ + bko;
    ushort_t* bdst = (bsel ? Bsi : Bsr) + nr * LDA + bko;

    const int fm = lane & 15, kq = (lane >> 4) * 8;
    const int wrow = wv * 32;

    for (int k0 = 0; k0 < SEQ; k0 += GBK) {
        float4 f0 = *(const float4*)(xa + k0);
        float4 f1 = *(const float4*)(xa + k0 + 4);
        float4 f2 = *(const float4*)(xa + k0 + 8);
        float4 f3 = *(const float4*)(xa + k0 + 12);
        uint4 a0, a1;
        a0.x = pkh(f0.x, f0.y); a0.y = pkh(f0.z, f0.w);
        a0.z = pkh(f1.x, f1.y); a0.w = pkh(f1.z, f1.w);
        a1.x = pkh(f2.x, f2.y); a1.y = pkh(f2.z, f2.w);
        a1.z = pkh(f3.x, f3.y); a1.w = pkh(f3.z, f3.w);
        *(uint4*)(Ash + sr * LDA + ko)     = a0;
        *(uint4*)(Ash + sr * LDA + ko + 8) = a1;
        uint4 b0 = *(const uint4*)(bsrc + k0);
        uint4 b1 = *(const uint4*)(bsrc + k0 + 8);
        *(uint4*)bdst       = b0;
        *(uint4*)(bdst + 8) = b1;
        __syncthreads();

        half8 ah0 = *(half8*)(Ash + (wrow + fm) * LDA + kq);
        half8 ah1 = *(half8*)(Ash + (wrow + 16 + fm) * LDA + kq);
#pragma unroll
        for (int nt = 0; nt < 4; ++nt) {
            half8 br = *(half8*)(Bsr + (nt * 16 + fm) * LDA + kq);
            half8 bi = *(half8*)(Bsi + (nt * 16 + fm) * LDA + kq);
            accr[0][nt] = __builtin_amdgcn_mfma_f32_16x16x32_f16(ah0, br, accr[0][nt], 0, 0, 0);
            accr[1][nt] = __builtin_amdgcn_mfma_f32_16x16x32_f16(ah1, br, accr[1][nt], 0, 0, 0);
            acci[0][nt] = __builtin_amdgcn_mfma_f32_16x16x32_f16(ah0, bi, acci[0][nt], 0, 0, 0);
            acci[1][nt] = __builtin_amdgcn_mfma_f32_16x16x32_f16(ah1, bi, acci[1][nt], 0, 0, 0);
        }
        __syncthreads();
    }

    // --- epilogue: p = zr^2 + zi^2 into LDS ---
    const int rq = (lane >> 4) * 4;
#pragma unroll
    for (int mt = 0; mt < 2; ++mt)
#pragma unroll
        for (int nt = 0; nt < 4; ++nt) {
            float drv = drs[nt * 16 + fm], div = dis[nt * 16 + fm];
#pragma unroll
            for (int reg = 0; reg < 4; ++reg) {
                int lrow = wrow + mt * 16 + rq + reg;
                float zr = accr[mt][nt][reg] + drv;
                float zi = acci[mt][nt][reg] + div;
                Ps[lrow * LDP + nt * 16 + fm] = zr * zr + zi * zi;
            }
        }
    __syncthreads();

    // --- signed partials over this block's 64 cols (low 6 bits of s) ---
    {
        const int row = tid >> 1, hh = tid & 1;
        const float* pr = Ps + row * LDP + hh * 32;
        float nrm = 0.f, e0 = 0.f, e1 = 0.f, e2 = 0.f, e3 = 0.f, e4 = 0.f, e5 = 0.f;
#pragma unroll
        for (int i = 0; i < 32; ++i) {
            float p = pr[i];
            int c = hh * 32 + i;
            nrm += p;
            e0 += ((c >> 5) & 1) ? -p : p;   // k=4
            e1 += ((c >> 4) & 1) ? -p : p;   // k=5
            e2 += ((c >> 3) & 1) ? -p : p;   // k=6
            e3 += ((c >> 2) & 1) ? -p : p;   // k=7
            e4 += ((c >> 1) & 1) ? -p : p;   // k=8
            e5 += (c & 1) ? -p : p;          // k=9
        }
        size_t base = ((size_t)(bm * GBM + row) * 32 + (bn * 2 + hh)) * 8;
        part[base + 0] = nrm;
        part[base + 1] = e0; part[base + 2] = e1; part[base + 3] = e2;
        part[base + 4] = e3; part[base + 5] = e4; part[base + 6] = e5;
    }
}

// ---------------------------------------------------------------------------
// Kernel 3: per-row wave-parallel combine of 32 partials + W_out epilogue.
// (Verbatim — passed.)
// ---------------------------------------------------------------------------
__global__ __launch_bounds__(128)
void finalize_kernel(const float* __restrict__ part, const float* __restrict__ W_out,
                     const float* __restrict__ b_out, float* __restrict__ out)
{
    __shared__ float evf[16];
    const int row = blockIdx.x, tid = threadIdx.x;

    if (tid < 64) {
        float v[11];
        if (tid < 32) {
            const float* p = part + ((size_t)row * 32 + tid) * 8;
            float4 a = *(const float4*)p;
            float4 b = *(const float4*)(p + 4);
            float nrm = a.x;
            int bnn = tid >> 1;   // s bits 9..6 = bits 3..0 of bnn
            v[0] = nrm;
            v[1] = (bnn & 8) ? -nrm : nrm;
            v[2] = (bnn & 4) ? -nrm : nrm;
            v[3] = (bnn & 2) ? -nrm : nrm;
            v[4] = (bnn & 1) ? -nrm : nrm;
            v[5] = a.y; v[6] = a.z; v[7] = a.w;
            v[8] = b.x; v[9] = b.y; v[10] = b.z;
        } else {
#pragma unroll
            for (int k = 0; k < 11; ++k) v[k] = 0.f;
        }
#pragma unroll
        for (int m = 16; m; m >>= 1)
#pragma unroll
            for (int k = 0; k < 11; ++k) v[k] += __shfl_xor(v[k], m, 64);
        if (tid == 0) {
            float inv = 1.0f / v[0];
#pragma unroll
            for (int k = 0; k < 10; ++k) evf[k] = v[k + 1] * inv;
        }
    }
    __syncthreads();
    if (tid < PRED) {
        float o = b_out[tid];
#pragma unroll
        for (int k = 0; k < NQ; ++k) o = fmaf(W_out[tid * NQ + k], evf[k], o);
        out[(size_t)row * PRED + tid] = o;
    }
}

extern "C" void kernel_launch(void* const* d_in, const int* in_sizes, int n_in,
                              void* d_out, int out_size, void* d_ws, size_t ws_size,
                              hipStream_t stream) {
    const float* x     = (const float*)d_in[0];
    const float* W_in  = (const float*)d_in[1];
    const float* b_in  = (const float*)d_in[2];
    const float* qw    = (const float*)d_in[3];
    const float* W_out = (const float*)d_in[4];
    const float* b_out = (const float*)d_in[5];
    float* out = (float*)d_out;

    char* w = (char*)d_ws;
    const size_t MB = 1u << 20;
    ushort_t* Crt_r = (ushort_t*)w;               // 1 MB  [s][j] f16
    ushort_t* Crt_i = (ushort_t*)(w + 1 * MB);    // 1 MB
    float*    dr    = (float*)(w + 2 * MB);       // 4 KB
    float*    di    = dr + DIM;                   // 4 KB
    float*    part  = (float*)(w + 3 * MB);       // 4 MB

    circuit_reg_kernel<<<(SEQ + 1 + CIRC_WAVES - 1) / CIRC_WAVES, 512, 0, stream>>>(
        W_in, b_in, qw, Crt_r, Crt_i, dr, di);
    dim3 g2(NROWS / GBM, DIM / GBNC);
    gemm_fused_kernel<<<g2, 256, 0, stream>>>(x, Crt_r, Crt_i, dr, di, part);
    finalize_kernel<<<NROWS, 128, 0, stream>>>(part, W_out, b_out, out);
}

// Round 2
// 111.607 us; speedup vs baseline: 1.2318x; 1.2318x over previous
//
#include <hip/hip_runtime.h>
#include <math.h>

#define DIM 1024
#define NQ 10
#define NL 4
#define SEQ 512
#define NROWS 4096
#define PRED 96

typedef unsigned short ushort_t;
typedef unsigned int uint_t;
using half8   = __attribute__((ext_vector_type(8))) _Float16;
using float4v = __attribute__((ext_vector_type(4))) float;

__device__ inline ushort_t f2h(float f) { _Float16 h = (_Float16)f; return *(ushort_t*)&h; }
__device__ inline uint_t pkh(float a, float b) {
    _Float16 ha = (_Float16)a, hb = (_Float16)b;   // RTE v_cvt_f16_f32
    return (uint_t)(*(ushort_t*)&ha) | ((uint_t)(*(ushort_t*)&hb) << 16);
}

// ---------------------------------------------------------------------------
// Kernel 0: x (fp32) -> xh (f16), same layout. 8 floats/thread.
// (Verbatim from the 114.6us-verified pipeline.)
// ---------------------------------------------------------------------------
__global__ __launch_bounds__(256)
void convert_x_kernel(const float* __restrict__ x, ushort_t* __restrict__ xh)
{
    int i = (blockIdx.x * 256 + threadIdx.x) * 8;
    float4 a = *(const float4*)(x + i);
    float4 b = *(const float4*)(x + i + 4);
    uint4 o;
    o.x = pkh(a.x, a.y); o.y = pkh(a.z, a.w);
    o.z = pkh(b.x, b.y); o.w = pkh(b.z, b.w);
    *(uint4*)(xh + i) = o;
}

// ---------------------------------------------------------------------------
// Kernel 1 (HYBRID): block-per-column (513 blocks, full GPU), 256 threads,
// 4 register states/thread: s = tid*4 + r.
//   s bit 9,8  -> cross-wave: LDS round (2 per layer, one fused with perm)
//   s bits 7:2 -> tid/lane bits: __shfl_xor, no barrier
//   s bits 1:0 -> register butterflies
// Layer perm is GF(2)-linear: P(s) = P(tid*4) ^ P(r); partner P(s^512) =
// P(s)^P(512). Perm gather fused with next layer's wire-0 LDS round.
// Total barriers: 9 (vs 45 in the original block-per-column kernel).
// LDS psi buffers: split re/im, index idx(s) = (s>>2) | ((s&3)<<8) = r*256+tid
// -> all structured accesses (own, ^64, ^128) are bank-conflict-free.
// ---------------------------------------------------------------------------
__global__ __launch_bounds__(256)
void circuit_hybrid_kernel(const float* __restrict__ Wi, const float* __restrict__ b_in,
                           const float* __restrict__ qw,
                           ushort_t* __restrict__ Crt_r, ushort_t* __restrict__ Crt_i,
                           float* __restrict__ dr, float* __restrict__ di)
{
    __shared__ float gm[NL * NQ][8];          // 1.25 KB
    __shared__ float bre[2][DIM];             // 8 KB
    __shared__ float bim[2][DIM];             // 8 KB

    const int tid = threadIdx.x;
    const int j = blockIdx.x;

    if (tid < NL * NQ) {
        float phi = qw[tid * 3 + 0], theta = qw[tid * 3 + 1], omega = qw[tid * 3 + 2];
        float ch = cosf(theta * 0.5f), sh = sinf(theta * 0.5f);
        float a = 0.5f * (phi + omega), b = 0.5f * (phi - omega);
        float ca = cosf(a), sa = sinf(a);
        float cb = cosf(b), sb = sinf(b);
        gm[tid][0] =  ch * ca;  gm[tid][1] = -ch * sa;   // m00
        gm[tid][2] = -sh * cb;  gm[tid][3] = -sh * sb;   // m01
        gm[tid][4] =  sh * cb;  gm[tid][5] = -sh * sb;   // m10
        gm[tid][6] =  ch * ca;  gm[tid][7] =  ch * sa;   // m11
    }

    // ---- load 4 states: s = tid*4 + r ----
    float2 st[4];
    if (j < SEQ) {
#pragma unroll
        for (int r = 0; r < 4; ++r)
            st[r] = make_float2(Wi[(size_t)(tid * 4 + r) * SEQ + j], 0.f);
    } else {
#pragma unroll
        for (int r = 0; r < 4; ++r)
            st[r] = make_float2(b_in[tid * 4 + r] + 1e-6f, 0.f);
    }
#pragma unroll
    for (int r = 0; r < 4; ++r) {
        bre[0][r * 256 + tid] = st[r].x;
        bim[0][r * 256 + tid] = st[r].y;
    }
    __syncthreads();                           // barrier 1
    int cur = 0;

    // ---- layer 0, wire 0 (bit 9): own = regs, partner from LDS ----
    {
        const float* m = gm[0];
        const int hi = tid >> 7;
        float cAr = hi ? m[6] : m[0], cAi = hi ? m[7] : m[1];
        float cBr = hi ? m[4] : m[2], cBi = hi ? m[5] : m[3];
#pragma unroll
        for (int r = 0; r < 4; ++r) {
            float px = bre[cur][r * 256 + (tid ^ 128)];
            float py = bim[cur][r * 256 + (tid ^ 128)];
            float nx = cAr * st[r].x - cAi * st[r].y + cBr * px - cBi * py;
            float ny = cAr * st[r].y + cAi * st[r].x + cBr * py + cBi * px;
            st[r] = make_float2(nx, ny);
        }
    }

#pragma unroll
    for (int l = 0; l < NL; ++l) {
        // ---- wire 1 (bit 8): LDS round ----
        {
#pragma unroll
            for (int r = 0; r < 4; ++r) {
                bre[cur ^ 1][r * 256 + tid] = st[r].x;
                bim[cur ^ 1][r * 256 + tid] = st[r].y;
            }
            __syncthreads();
            cur ^= 1;
            const float* m = gm[l * NQ + 1];
            const int hi = (tid >> 6) & 1;
            float cAr = hi ? m[6] : m[0], cAi = hi ? m[7] : m[1];
            float cBr = hi ? m[4] : m[2], cBi = hi ? m[5] : m[3];
#pragma unroll
            for (int r = 0; r < 4; ++r) {
                float px = bre[cur][r * 256 + (tid ^ 64)];
                float py = bim[cur][r * 256 + (tid ^ 64)];
                float nx = cAr * st[r].x - cAi * st[r].y + cBr * px - cBi * py;
                float ny = cAr * st[r].y + cAi * st[r].x + cBr * py + cBi * px;
                st[r] = make_float2(nx, ny);
            }
        }
        // ---- wires 2..7 (s bits 7..2 = tid bits 5..0): shuffles ----
#pragma unroll
        for (int w = 2; w < 8; ++w) {
            const float* m = gm[l * NQ + w];
            const int lb = 7 - w;              // tid bit
            const int hi = (tid >> lb) & 1;
            float cAr = hi ? m[6] : m[0], cAi = hi ? m[7] : m[1];
            float cBr = hi ? m[4] : m[2], cBi = hi ? m[5] : m[3];
            const int mask = 1 << lb;
#pragma unroll
            for (int r = 0; r < 4; ++r) {
                float px = __shfl_xor(st[r].x, mask, 64);
                float py = __shfl_xor(st[r].y, mask, 64);
                float nx = cAr * st[r].x - cAi * st[r].y + cBr * px - cBi * py;
                float ny = cAr * st[r].y + cAi * st[r].x + cBr * py + cBi * px;
                st[r] = make_float2(nx, ny);
            }
        }
        // ---- wire 8 (bit 1): reg pairs (0,2),(1,3) ----
        {
            const float* m = gm[l * NQ + 8];
            float m00r = m[0], m00i = m[1], m01r = m[2], m01i = m[3];
            float m10r = m[4], m10i = m[5], m11r = m[6], m11i = m[7];
#pragma unroll
            for (int r0 = 0; r0 < 2; ++r0) {
                float2 a0 = st[r0], a1 = st[r0 + 2];
                st[r0].x     = m00r * a0.x - m00i * a0.y + m01r * a1.x - m01i * a1.y;
                st[r0].y     = m00r * a0.y + m00i * a0.x + m01r * a1.y + m01i * a1.x;
                st[r0 + 2].x = m10r * a0.x - m10i * a0.y + m11r * a1.x - m11i * a1.y;
                st[r0 + 2].y = m10r * a0.y + m10i * a0.x + m11r * a1.y + m11i * a1.x;
            }
        }
        // ---- wire 9 (bit 0): reg pairs (0,1),(2,3) ----
        {
            const float* m = gm[l * NQ + 9];
            float m00r = m[0], m00i = m[1], m01r = m[2], m01i = m[3];
            float m10r = m[4], m10i = m[5], m11r = m[6], m11i = m[7];
#pragma unroll
            for (int r0 = 0; r0 < 4; r0 += 2) {
                float2 a0 = st[r0], a1 = st[r0 + 1];
                st[r0].x     = m00r * a0.x - m00i * a0.y + m01r * a1.x - m01i * a1.y;
                st[r0].y     = m00r * a0.y + m00i * a0.x + m01r * a1.y + m01i * a1.x;
                st[r0 + 1].x = m10r * a0.x - m10i * a0.y + m11r * a1.x - m11i * a1.y;
                st[r0 + 1].y = m10r * a0.y + m10i * a0.x + m11r * a1.y + m11i * a1.x;
            }
        }
        // ---- layer perm (write, barrier, gather), fused with next wire 0 ----
        {
#pragma unroll
            for (int r = 0; r < 4; ++r) {
                bre[cur ^ 1][r * 256 + tid] = st[r].x;
                bim[cur ^ 1][r * 256 + tid] = st[r].y;
            }
            __syncthreads();
            cur ^= 1;

            const int rr = l % (NQ - 1) + 1;
            // P is GF(2)-linear (XOR-shear cascade): compute P(tid*4) and the
            // constants P(1),P(2),P(512) (compile-time folded, rr is constant).
            int pbase = tid * 4;
            int p1 = 1, p2 = 2, p512 = 512;
#pragma unroll
            for (int c = 9; c >= 0; --c) {
                const int t = (c + rr) % NQ;
                pbase ^= ((pbase >> (9 - c)) & 1) << (9 - t);
                p1    ^= ((p1    >> (9 - c)) & 1) << (9 - t);
                p2    ^= ((p2    >> (9 - c)) & 1) << (9 - t);
                p512  ^= ((p512  >> (9 - c)) & 1) << (9 - t);
            }
            const int p3 = p1 ^ p2;
            const int prr0 = pbase, prr1 = pbase ^ p1, prr2 = pbase ^ p2, prr3 = pbase ^ p3;
            int Ps[4] = {prr0, prr1, prr2, prr3};

            if (l < NL - 1) {
                const float* m = gm[(l + 1) * NQ + 0];
                const int hi = tid >> 7;       // bit 9 of NEW index s
                float cAr = hi ? m[6] : m[0], cAi = hi ? m[7] : m[1];
                float cBr = hi ? m[4] : m[2], cBi = hi ? m[5] : m[3];
#pragma unroll
                for (int r = 0; r < 4; ++r) {
                    int so = Ps[r];
                    int sp = so ^ p512;
                    int io = (so >> 2) | ((so & 3) << 8);
                    int ip = (sp >> 2) | ((sp & 3) << 8);
                    float ox = bre[cur][io], oy = bim[cur][io];
                    float px = bre[cur][ip], py = bim[cur][ip];
                    float nx = cAr * ox - cAi * oy + cBr * px - cBi * py;
                    float ny = cAr * oy + cAi * ox + cBr * py + cBi * px;
                    st[r] = make_float2(nx, ny);
                }
            } else {
#pragma unroll
                for (int r = 0; r < 4; ++r) {
                    int so = Ps[r];
                    int io = (so >> 2) | ((so & 3) << 8);
                    st[r] = make_float2(bre[cur][io], bim[cur][io]);
                }
            }
        }
    }

    // ---- store ----
    if (j < SEQ) {
#pragma unroll
        for (int r = 0; r < 4; ++r) {
            Crt_r[(size_t)(tid * 4 + r) * SEQ + j] = f2h(st[r].x);
            Crt_i[(size_t)(tid * 4 + r) * SEQ + j] = f2h(st[r].y);
        }
    } else {
#pragma unroll
        for (int r = 0; r < 4; ++r) {
            dr[tid * 4 + r] = st[r].x;
            di[tid * 4 + r] = st[r].y;
        }
    }
}

// ---------------------------------------------------------------------------
// Kernel 2: fused f16-MFMA GEMM + probs + signed partials.
// (Verbatim from the 114.6us-verified pipeline: xh pre-converted input.)
// ---------------------------------------------------------------------------
#define GBM 128
#define GBNC 64
#define GBK 32
#define LDA 40   // half stride for LDS tiles
#define LDP 65   // float stride for probs tile

__global__ __launch_bounds__(256)
void gemm_fused_kernel(const ushort_t* __restrict__ xh,
                       const ushort_t* __restrict__ Crt_r, const ushort_t* __restrict__ Crt_i,
                       const float* __restrict__ dr, const float* __restrict__ di,
                       float* __restrict__ part)
{
    __shared__ __align__(16) char lds[GBM * LDP * 4];  // 33280 B (probs tile is max)
    ushort_t* Ash = (ushort_t*)lds;            // 128*40 halves = 10240 B
    ushort_t* Bsr = Ash + GBM * LDA;           // 64*40 = 5120 B
    ushort_t* Bsi = Bsr + GBNC * LDA;          // 64*40 = 5120 B
    float*    Ps  = (float*)lds;               // reused after K-loop
    __shared__ float drs[GBNC], dis[GBNC];

    const int tid = threadIdx.x;
    const int bm = blockIdx.x, bn = blockIdx.y;
    const int lane = tid & 63, wv = tid >> 6;
    const int n0 = bn * GBNC;

    if (tid < GBNC) { drs[tid] = dr[n0 + tid]; dis[tid] = di[n0 + tid]; }

    float4v accr[2][4], acci[2][4];
#pragma unroll
    for (int a = 0; a < 2; ++a)
#pragma unroll
        for (int b = 0; b < 4; ++b) { accr[a][b] = (float4v)0.f; acci[a][b] = (float4v)0.f; }

    // A staging: thread -> row sr (0..127), k offset ko (0 or 16); 16 halves
    const int sr = tid >> 1, ko = (tid & 1) * 16;
    const ushort_t* xa = xh + (size_t)(bm * GBM + sr) * SEQ + ko;
    // B staging: threads 0-127 real, 128-255 imag; 16 halves each
    const int bsel = tid >> 7;
    const int nr = (tid & 127) >> 1;
    const int bko = (tid & 1) * 16;
    const ushort_t* bsrc = (bsel ? Crt_i : Crt_r) + (size_t)(n0 + nr) * SEQ + bko;
    ushort_t* bdst = (bsel ? Bsi : Bsr) + nr * LDA + bko;

    const int fm = lane & 15, kq = (lane >> 4) * 8;
    const int wrow = wv * 32;

    for (int k0 = 0; k0 < SEQ; k0 += GBK) {
        uint4 a0 = *(const uint4*)(xa + k0);
        uint4 a1 = *(const uint4*)(xa + k0 + 8);
        *(uint4*)(Ash + sr * LDA + ko)     = a0;
        *(uint4*)(Ash + sr * LDA + ko + 8) = a1;
        uint4 b0 = *(const uint4*)(bsrc + k0);
        uint4 b1 = *(const uint4*)(bsrc + k0 + 8);
        *(uint4*)bdst       = b0;
        *(uint4*)(bdst + 8) = b1;
        __syncthreads();

        half8 ah0 = *(half8*)(Ash + (wrow + fm) * LDA + kq);
        half8 ah1 = *(half8*)(Ash + (wrow + 16 + fm) * LDA + kq);
#pragma unroll
        for (int nt = 0; nt < 4; ++nt) {
            half8 br = *(half8*)(Bsr + (nt * 16 + fm) * LDA + kq);
            half8 bi = *(half8*)(Bsi + (nt * 16 + fm) * LDA + kq);
            accr[0][nt] = __builtin_amdgcn_mfma_f32_16x16x32_f16(ah0, br, accr[0][nt], 0, 0, 0);
            accr[1][nt] = __builtin_amdgcn_mfma_f32_16x16x32_f16(ah1, br, accr[1][nt], 0, 0, 0);
            acci[0][nt] = __builtin_amdgcn_mfma_f32_16x16x32_f16(ah0, bi, acci[0][nt], 0, 0, 0);
            acci[1][nt] = __builtin_amdgcn_mfma_f32_16x16x32_f16(ah1, bi, acci[1][nt], 0, 0, 0);
        }
        __syncthreads();
    }

    // --- epilogue: p = zr^2 + zi^2 into LDS ---
    const int rq = (lane >> 4) * 4;
#pragma unroll
    for (int mt = 0; mt < 2; ++mt)
#pragma unroll
        for (int nt = 0; nt < 4; ++nt) {
            float drv = drs[nt * 16 + fm], div = dis[nt * 16 + fm];
#pragma unroll
            for (int reg = 0; reg < 4; ++reg) {
                int lrow = wrow + mt * 16 + rq + reg;
                float zr = accr[mt][nt][reg] + drv;
                float zi = acci[mt][nt][reg] + div;
                Ps[lrow * LDP + nt * 16 + fm] = zr * zr + zi * zi;
            }
        }
    __syncthreads();

    // --- signed partials over this block's 64 cols (low 6 bits of s) ---
    {
        const int row = tid >> 1, hh = tid & 1;
        const float* pr = Ps + row * LDP + hh * 32;
        float nrm = 0.f, e0 = 0.f, e1 = 0.f, e2 = 0.f, e3 = 0.f, e4 = 0.f, e5 = 0.f;
#pragma unroll
        for (int i = 0; i < 32; ++i) {
            float p = pr[i];
            int c = hh * 32 + i;
            nrm += p;
            e0 += ((c >> 5) & 1) ? -p : p;   // k=4
            e1 += ((c >> 4) & 1) ? -p : p;   // k=5
            e2 += ((c >> 3) & 1) ? -p : p;   // k=6
            e3 += ((c >> 2) & 1) ? -p : p;   // k=7
            e4 += ((c >> 1) & 1) ? -p : p;   // k=8
            e5 += (c & 1) ? -p : p;          // k=9
        }
        size_t base = ((size_t)(bm * GBM + row) * 32 + (bn * 2 + hh)) * 8;
        part[base + 0] = nrm;
        part[base + 1] = e0; part[base + 2] = e1; part[base + 3] = e2;
        part[base + 4] = e3; part[base + 5] = e4; part[base + 6] = e5;
    }
}

// ---------------------------------------------------------------------------
// Kernel 3: per-row wave-parallel combine of 32 partials + W_out epilogue.
// (Verbatim — verified.)
// ---------------------------------------------------------------------------
__global__ __launch_bounds__(128)
void finalize_kernel(const float* __restrict__ part, const float* __restrict__ W_out,
                     const float* __restrict__ b_out, float* __restrict__ out)
{
    __shared__ float evf[16];
    const int row = blockIdx.x, tid = threadIdx.x;

    if (tid < 64) {
        float v[11];
        if (tid < 32) {
            const float* p = part + ((size_t)row * 32 + tid) * 8;
            float4 a = *(const float4*)p;
            float4 b = *(const float4*)(p + 4);
            float nrm = a.x;
            int bnn = tid >> 1;   // s bits 9..6 = bits 3..0 of bnn
            v[0] = nrm;
            v[1] = (bnn & 8) ? -nrm : nrm;
            v[2] = (bnn & 4) ? -nrm : nrm;
            v[3] = (bnn & 2) ? -nrm : nrm;
            v[4] = (bnn & 1) ? -nrm : nrm;
            v[5] = a.y; v[6] = a.z; v[7] = a.w;
            v[8] = b.x; v[9] = b.y; v[10] = b.z;
        } else {
#pragma unroll
            for (int k = 0; k < 11; ++k) v[k] = 0.f;
        }
#pragma unroll
        for (int m = 16; m; m >>= 1)
#pragma unroll
            for (int k = 0; k < 11; ++k) v[k] += __shfl_xor(v[k], m, 64);
        if (tid == 0) {
            float inv = 1.0f / v[0];
#pragma unroll
            for (int k = 0; k < 10; ++k) evf[k] = v[k + 1] * inv;
        }
    }
    __syncthreads();
    if (tid < PRED) {
        float o = b_out[tid];
#pragma unroll
        for (int k = 0; k < NQ; ++k) o = fmaf(W_out[tid * NQ + k], evf[k], o);
        out[(size_t)row * PRED + tid] = o;
    }
}

extern "C" void kernel_launch(void* const* d_in, const int* in_sizes, int n_in,
                              void* d_out, int out_size, void* d_ws, size_t ws_size,
                              hipStream_t stream) {
    const float* x     = (const float*)d_in[0];
    const float* W_in  = (const float*)d_in[1];
    const float* b_in  = (const float*)d_in[2];
    const float* qw    = (const float*)d_in[3];
    const float* W_out = (const float*)d_in[4];
    const float* b_out = (const float*)d_in[5];
    float* out = (float*)d_out;

    char* w = (char*)d_ws;
    const size_t MB = 1u << 20;
    ushort_t* xh    = (ushort_t*)w;               // 4 MB  f16 x
    ushort_t* Crt_r = (ushort_t*)(w + 4 * MB);    // 1 MB  [s][j]
    ushort_t* Crt_i = (ushort_t*)(w + 5 * MB);    // 1 MB
    float*    dr    = (float*)(w + 6 * MB);       // 4 KB
    float*    di    = dr + DIM;                   // 4 KB
    float*    part  = (float*)(w + 7 * MB);       // 4 MB

    convert_x_kernel<<<NROWS * SEQ / (256 * 8), 256, 0, stream>>>(x, xh);
    circuit_hybrid_kernel<<<SEQ + 1, 256, 0, stream>>>(W_in, b_in, qw, Crt_r, Crt_i, dr, di);
    dim3 g2(NROWS / GBM, DIM / GBNC);
    gemm_fused_kernel<<<g2, 256, 0, stream>>>(xh, Crt_r, Crt_i, dr, di, part);
    finalize_kernel<<<NROWS, 128, 0, stream>>>(part, W_out, b_out, out);
}

// Round 6
// 110.408 us; speedup vs baseline: 1.2452x; 1.0109x over previous
//
#include <hip/hip_runtime.h>
#include <math.h>

#define DIM 1024
#define NQ 10
#define NL 4
#define SEQ 512
#define NROWS 4096
#define PRED 96

typedef unsigned short ushort_t;
typedef unsigned int uint_t;
using half8   = __attribute__((ext_vector_type(8))) _Float16;
using float4v = __attribute__((ext_vector_type(4))) float;

__device__ inline ushort_t f2h(float f) { _Float16 h = (_Float16)f; return *(ushort_t*)&h; }
__device__ inline uint_t pkh(float a, float b) {
    _Float16 ha = (_Float16)a, hb = (_Float16)b;   // RTE v_cvt_f16_f32
    return (uint_t)(*(ushort_t*)&ha) | ((uint_t)(*(ushort_t*)&hb) << 16);
}

// ---------------------------------------------------------------------------
// Kernel 0: x (fp32) -> xh (f16), same layout. 8 floats/thread.
// (Verbatim from the R2-verified 111.6us pipeline.)
// ---------------------------------------------------------------------------
__global__ __launch_bounds__(256)
void convert_x_kernel(const float* __restrict__ x, ushort_t* __restrict__ xh)
{
    int i = (blockIdx.x * 256 + threadIdx.x) * 8;
    float4 a = *(const float4*)(x + i);
    float4 b = *(const float4*)(x + i + 4);
    uint4 o;
    o.x = pkh(a.x, a.y); o.y = pkh(a.z, a.w);
    o.z = pkh(b.x, b.y); o.w = pkh(b.z, b.w);
    *(uint4*)(xh + i) = o;
}

// ---------------------------------------------------------------------------
// Kernel 1: hybrid circuit (verbatim from the R2-verified 111.6us pipeline).
// ---------------------------------------------------------------------------
__global__ __launch_bounds__(256)
void circuit_hybrid_kernel(const float* __restrict__ Wi, const float* __restrict__ b_in,
                           const float* __restrict__ qw,
                           ushort_t* __restrict__ Crt_r, ushort_t* __restrict__ Crt_i,
                           float* __restrict__ dr, float* __restrict__ di)
{
    __shared__ float gm[NL * NQ][8];
    __shared__ float bre[2][DIM];
    __shared__ float bim[2][DIM];

    const int tid = threadIdx.x;
    const int j = blockIdx.x;

    if (tid < NL * NQ) {
        float phi = qw[tid * 3 + 0], theta = qw[tid * 3 + 1], omega = qw[tid * 3 + 2];
        float ch = cosf(theta * 0.5f), sh = sinf(theta * 0.5f);
        float a = 0.5f * (phi + omega), b = 0.5f * (phi - omega);
        float ca = cosf(a), sa = sinf(a);
        float cb = cosf(b), sb = sinf(b);
        gm[tid][0] =  ch * ca;  gm[tid][1] = -ch * sa;   // m00
        gm[tid][2] = -sh * cb;  gm[tid][3] = -sh * sb;   // m01
        gm[tid][4] =  sh * cb;  gm[tid][5] = -sh * sb;   // m10
        gm[tid][6] =  ch * ca;  gm[tid][7] =  ch * sa;   // m11
    }

    // ---- load 4 states: s = tid*4 + r ----
    float2 st[4];
    if (j < SEQ) {
#pragma unroll
        for (int r = 0; r < 4; ++r)
            st[r] = make_float2(Wi[(size_t)(tid * 4 + r) * SEQ + j], 0.f);
    } else {
#pragma unroll
        for (int r = 0; r < 4; ++r)
            st[r] = make_float2(b_in[tid * 4 + r] + 1e-6f, 0.f);
    }
#pragma unroll
    for (int r = 0; r < 4; ++r) {
        bre[0][r * 256 + tid] = st[r].x;
        bim[0][r * 256 + tid] = st[r].y;
    }
    __syncthreads();
    int cur = 0;

    // ---- layer 0, wire 0 (bit 9) ----
    {
        const float* m = gm[0];
        const int hi = tid >> 7;
        float cAr = hi ? m[6] : m[0], cAi = hi ? m[7] : m[1];
        float cBr = hi ? m[4] : m[2], cBi = hi ? m[5] : m[3];
#pragma unroll
        for (int r = 0; r < 4; ++r) {
            float px = bre[cur][r * 256 + (tid ^ 128)];
            float py = bim[cur][r * 256 + (tid ^ 128)];
            float nx = cAr * st[r].x - cAi * st[r].y + cBr * px - cBi * py;
            float ny = cAr * st[r].y + cAi * st[r].x + cBr * py + cBi * px;
            st[r] = make_float2(nx, ny);
        }
    }

#pragma unroll
    for (int l = 0; l < NL; ++l) {
        // ---- wire 1 (bit 8): LDS round ----
        {
#pragma unroll
            for (int r = 0; r < 4; ++r) {
                bre[cur ^ 1][r * 256 + tid] = st[r].x;
                bim[cur ^ 1][r * 256 + tid] = st[r].y;
            }
            __syncthreads();
            cur ^= 1;
            const float* m = gm[l * NQ + 1];
            const int hi = (tid >> 6) & 1;
            float cAr = hi ? m[6] : m[0], cAi = hi ? m[7] : m[1];
            float cBr = hi ? m[4] : m[2], cBi = hi ? m[5] : m[3];
#pragma unroll
            for (int r = 0; r < 4; ++r) {
                float px = bre[cur][r * 256 + (tid ^ 64)];
                float py = bim[cur][r * 256 + (tid ^ 64)];
                float nx = cAr * st[r].x - cAi * st[r].y + cBr * px - cBi * py;
                float ny = cAr * st[r].y + cAi * st[r].x + cBr * py + cBi * px;
                st[r] = make_float2(nx, ny);
            }
        }
        // ---- wires 2..7: shuffles ----
#pragma unroll
        for (int w = 2; w < 8; ++w) {
            const float* m = gm[l * NQ + w];
            const int lb = 7 - w;
            const int hi = (tid >> lb) & 1;
            float cAr = hi ? m[6] : m[0], cAi = hi ? m[7] : m[1];
            float cBr = hi ? m[4] : m[2], cBi = hi ? m[5] : m[3];
            const int mask = 1 << lb;
#pragma unroll
            for (int r = 0; r < 4; ++r) {
                float px = __shfl_xor(st[r].x, mask, 64);
                float py = __shfl_xor(st[r].y, mask, 64);
                float nx = cAr * st[r].x - cAi * st[r].y + cBr * px - cBi * py;
                float ny = cAr * st[r].y + cAi * st[r].x + cBr * py + cBi * px;
                st[r] = make_float2(nx, ny);
            }
        }
        // ---- wire 8 (bit 1) ----
        {
            const float* m = gm[l * NQ + 8];
            float m00r = m[0], m00i = m[1], m01r = m[2], m01i = m[3];
            float m10r = m[4], m10i = m[5], m11r = m[6], m11i = m[7];
#pragma unroll
            for (int r0 = 0; r0 < 2; ++r0) {
                float2 a0 = st[r0], a1 = st[r0 + 2];
                st[r0].x     = m00r * a0.x - m00i * a0.y + m01r * a1.x - m01i * a1.y;
                st[r0].y     = m00r * a0.y + m00i * a0.x + m01r * a1.y + m01i * a1.x;
                st[r0 + 2].x = m10r * a0.x - m10i * a0.y + m11r * a1.x - m11i * a1.y;
                st[r0 + 2].y = m10r * a0.y + m10i * a0.x + m11r * a1.y + m11i * a1.x;
            }
        }
        // ---- wire 9 (bit 0) ----
        {
            const float* m = gm[l * NQ + 9];
            float m00r = m[0], m00i = m[1], m01r = m[2], m01i = m[3];
            float m10r = m[4], m10i = m[5], m11r = m[6], m11i = m[7];
#pragma unroll
            for (int r0 = 0; r0 < 4; r0 += 2) {
                float2 a0 = st[r0], a1 = st[r0 + 1];
                st[r0].x     = m00r * a0.x - m00i * a0.y + m01r * a1.x - m01i * a1.y;
                st[r0].y     = m00r * a0.y + m00i * a0.x + m01r * a1.y + m01i * a1.x;
                st[r0 + 1].x = m10r * a0.x - m10i * a0.y + m11r * a1.x - m11i * a1.y;
                st[r0 + 1].y = m10r * a0.y + m10i * a0.x + m11r * a1.y + m11i * a1.x;
            }
        }
        // ---- layer perm, fused with next layer's wire 0 ----
        {
#pragma unroll
            for (int r = 0; r < 4; ++r) {
                bre[cur ^ 1][r * 256 + tid] = st[r].x;
                bim[cur ^ 1][r * 256 + tid] = st[r].y;
            }
            __syncthreads();
            cur ^= 1;

            const int rr = l % (NQ - 1) + 1;
            int pbase = tid * 4;
            int p1 = 1, p2 = 2, p512 = 512;
#pragma unroll
            for (int c = 9; c >= 0; --c) {
                const int t = (c + rr) % NQ;
                pbase ^= ((pbase >> (9 - c)) & 1) << (9 - t);
                p1    ^= ((p1    >> (9 - c)) & 1) << (9 - t);
                p2    ^= ((p2    >> (9 - c)) & 1) << (9 - t);
                p512  ^= ((p512  >> (9 - c)) & 1) << (9 - t);
            }
            const int p3 = p1 ^ p2;
            int Ps[4] = {pbase, pbase ^ p1, pbase ^ p2, pbase ^ p3};

            if (l < NL - 1) {
                const float* m = gm[(l + 1) * NQ + 0];
                const int hi = tid >> 7;
                float cAr = hi ? m[6] : m[0], cAi = hi ? m[7] : m[1];
                float cBr = hi ? m[4] : m[2], cBi = hi ? m[5] : m[3];
#pragma unroll
                for (int r = 0; r < 4; ++r) {
                    int so = Ps[r];
                    int sp = so ^ p512;
                    int io = (so >> 2) | ((so & 3) << 8);
                    int ip = (sp >> 2) | ((sp & 3) << 8);
                    float ox = bre[cur][io], oy = bim[cur][io];
                    float px = bre[cur][ip], py = bim[cur][ip];
                    float nx = cAr * ox - cAi * oy + cBr * px - cBi * py;
                    float ny = cAr * oy + cAi * ox + cBr * py + cBi * px;
                    st[r] = make_float2(nx, ny);
                }
            } else {
#pragma unroll
                for (int r = 0; r < 4; ++r) {
                    int so = Ps[r];
                    int io = (so >> 2) | ((so & 3) << 8);
                    st[r] = make_float2(bre[cur][io], bim[cur][io]);
                }
            }
        }
    }

    // ---- store ----
    if (j < SEQ) {
#pragma unroll
        for (int r = 0; r < 4; ++r) {
            Crt_r[(size_t)(tid * 4 + r) * SEQ + j] = f2h(st[r].x);
            Crt_i[(size_t)(tid * 4 + r) * SEQ + j] = f2h(st[r].y);
        }
    } else {
#pragma unroll
        for (int r = 0; r < 4; ++r) {
            dr[tid * 4 + r] = st[r].x;
            di[tid * 4 + r] = st[r].y;
        }
    }
}

// ---------------------------------------------------------------------------
// Kernel 2: fused f16-MFMA GEMM + probs + signed partials.
// EXACT R2-verified loop schedule (loads at top of iteration, store, barrier,
// compute, barrier — NO loop-carried prefetch registers). Only parameter
// change: GBK 32 -> 64 (LDA 40 -> 72): half the iterations, half the
// barrier drains, 2x MFMA per phase. Accumulation order is bit-identical
// (sub0 then sub1 == old iterations 2t, 2t+1). Bank behavior unchanged
// (rows r, r+8 collide -> 2-way, free).
// ---------------------------------------------------------------------------
#define GBM 128
#define GBNC 64
#define GBK 64
#define LDA 72   // half stride for LDS tiles (64 + 8 pad)
#define LDP 65   // float stride for probs tile

__global__ __launch_bounds__(256)
void gemm_fused_kernel(const ushort_t* __restrict__ xh,
                       const ushort_t* __restrict__ Crt_r, const ushort_t* __restrict__ Crt_i,
                       const float* __restrict__ dr, const float* __restrict__ di,
                       float* __restrict__ part)
{
    // staging: A 128*72 + Br 64*72 + Bi 64*72 halves = 36864 B; probs 33280 B
    __shared__ __align__(16) char lds[(GBM + 2 * GBNC) * LDA * 2];
    ushort_t* Ash = (ushort_t*)lds;            // 128*72 halves
    ushort_t* Bsr = Ash + GBM * LDA;           // 64*72
    ushort_t* Bsi = Bsr + GBNC * LDA;          // 64*72
    float*    Ps  = (float*)lds;               // reused after K-loop
    __shared__ float drs[GBNC], dis[GBNC];

    const int tid = threadIdx.x;
    const int bm = blockIdx.x, bn = blockIdx.y;
    const int lane = tid & 63, wv = tid >> 6;
    const int n0 = bn * GBNC;

    if (tid < GBNC) { drs[tid] = dr[n0 + tid]; dis[tid] = di[n0 + tid]; }

    float4v accr[2][4], acci[2][4];
#pragma unroll
    for (int a = 0; a < 2; ++a)
#pragma unroll
        for (int b = 0; b < 4; ++b) { accr[a][b] = (float4v)0.f; acci[a][b] = (float4v)0.f; }

    // A staging: row sr (0..127), k offset ko (0 or 32); 32 halves/thread
    const int sr = tid >> 1, ko = (tid & 1) * 32;
    const ushort_t* xa = xh + (size_t)(bm * GBM + sr) * SEQ + ko;
    // B staging: threads 0-127 real, 128-255 imag; 32 halves each
    const int bsel = tid >> 7;
    const int nr = (tid & 127) >> 1;
    const int bko = (tid & 1) * 32;
    const ushort_t* bsrc = (bsel ? Crt_i : Crt_r) + (size_t)(n0 + nr) * SEQ + bko;
    ushort_t* bdst = (bsel ? Bsi : Bsr) + nr * LDA + bko;

    const int fm = lane & 15, kq = (lane >> 4) * 8;
    const int wrow = wv * 32;

    for (int k0 = 0; k0 < SEQ; k0 += GBK) {
        uint4 a0 = *(const uint4*)(xa + k0);
        uint4 a1 = *(const uint4*)(xa + k0 + 8);
        uint4 a2 = *(const uint4*)(xa + k0 + 16);
        uint4 a3 = *(const uint4*)(xa + k0 + 24);
        *(uint4*)(Ash + sr * LDA + ko)      = a0;
        *(uint4*)(Ash + sr * LDA + ko + 8)  = a1;
        *(uint4*)(Ash + sr * LDA + ko + 16) = a2;
        *(uint4*)(Ash + sr * LDA + ko + 24) = a3;
        uint4 b0 = *(const uint4*)(bsrc + k0);
        uint4 b1 = *(const uint4*)(bsrc + k0 + 8);
        uint4 b2 = *(const uint4*)(bsrc + k0 + 16);
        uint4 b3 = *(const uint4*)(bsrc + k0 + 24);
        *(uint4*)bdst        = b0;
        *(uint4*)(bdst + 8)  = b1;
        *(uint4*)(bdst + 16) = b2;
        *(uint4*)(bdst + 24) = b3;
        __syncthreads();

        // sub-tile 0 (k = k0 .. k0+31)
        {
            half8 ah0 = *(half8*)(Ash + (wrow + fm) * LDA + kq);
            half8 ah1 = *(half8*)(Ash + (wrow + 16 + fm) * LDA + kq);
#pragma unroll
            for (int nt = 0; nt < 4; ++nt) {
                half8 br = *(half8*)(Bsr + (nt * 16 + fm) * LDA + kq);
                half8 bi = *(half8*)(Bsi + (nt * 16 + fm) * LDA + kq);
                accr[0][nt] = __builtin_amdgcn_mfma_f32_16x16x32_f16(ah0, br, accr[0][nt], 0, 0, 0);
                accr[1][nt] = __builtin_amdgcn_mfma_f32_16x16x32_f16(ah1, br, accr[1][nt], 0, 0, 0);
                acci[0][nt] = __builtin_amdgcn_mfma_f32_16x16x32_f16(ah0, bi, acci[0][nt], 0, 0, 0);
                acci[1][nt] = __builtin_amdgcn_mfma_f32_16x16x32_f16(ah1, bi, acci[1][nt], 0, 0, 0);
            }
        }
        // sub-tile 1 (k = k0+32 .. k0+63)
        {
            half8 ah0 = *(half8*)(Ash + (wrow + fm) * LDA + 32 + kq);
            half8 ah1 = *(half8*)(Ash + (wrow + 16 + fm) * LDA + 32 + kq);
#pragma unroll
            for (int nt = 0; nt < 4; ++nt) {
                half8 br = *(half8*)(Bsr + (nt * 16 + fm) * LDA + 32 + kq);
                half8 bi = *(half8*)(Bsi + (nt * 16 + fm) * LDA + 32 + kq);
                accr[0][nt] = __builtin_amdgcn_mfma_f32_16x16x32_f16(ah0, br, accr[0][nt], 0, 0, 0);
                accr[1][nt] = __builtin_amdgcn_mfma_f32_16x16x32_f16(ah1, br, accr[1][nt], 0, 0, 0);
                acci[0][nt] = __builtin_amdgcn_mfma_f32_16x16x32_f16(ah0, bi, acci[0][nt], 0, 0, 0);
                acci[1][nt] = __builtin_amdgcn_mfma_f32_16x16x32_f16(ah1, bi, acci[1][nt], 0, 0, 0);
            }
        }
        __syncthreads();
    }

    // --- epilogue: p = zr^2 + zi^2 into LDS ---
    const int rq = (lane >> 4) * 4;
#pragma unroll
    for (int mt = 0; mt < 2; ++mt)
#pragma unroll
        for (int nt = 0; nt < 4; ++nt) {
            float drv = drs[nt * 16 + fm], div = dis[nt * 16 + fm];
#pragma unroll
            for (int reg = 0; reg < 4; ++reg) {
                int lrow = wrow + mt * 16 + rq + reg;
                float zr = accr[mt][nt][reg] + drv;
                float zi = acci[mt][nt][reg] + div;
                Ps[lrow * LDP + nt * 16 + fm] = zr * zr + zi * zi;
            }
        }
    __syncthreads();

    // --- signed partials over this block's 64 cols ---
    {
        const int row = tid >> 1, hh = tid & 1;
        const float* pr = Ps + row * LDP + hh * 32;
        float nrm = 0.f, e0 = 0.f, e1 = 0.f, e2 = 0.f, e3 = 0.f, e4 = 0.f, e5 = 0.f;
#pragma unroll
        for (int i = 0; i < 32; ++i) {
            float p = pr[i];
            int c = hh * 32 + i;
            nrm += p;
            e0 += ((c >> 5) & 1) ? -p : p;
            e1 += ((c >> 4) & 1) ? -p : p;
            e2 += ((c >> 3) & 1) ? -p : p;
            e3 += ((c >> 2) & 1) ? -p : p;
            e4 += ((c >> 1) & 1) ? -p : p;
            e5 += (c & 1) ? -p : p;
        }
        size_t base2 = ((size_t)(bm * GBM + row) * 32 + (bn * 2 + hh)) * 8;
        part[base2 + 0] = nrm;
        part[base2 + 1] = e0; part[base2 + 2] = e1; part[base2 + 3] = e2;
        part[base2 + 4] = e3; part[base2 + 5] = e4; part[base2 + 6] = e5;
    }
}

// ---------------------------------------------------------------------------
// Kernel 3: per-row wave-parallel combine of 32 partials + W_out epilogue.
// (Verbatim — verified.)
// ---------------------------------------------------------------------------
__global__ __launch_bounds__(128)
void finalize_kernel(const float* __restrict__ part, const float* __restrict__ W_out,
                     const float* __restrict__ b_out, float* __restrict__ out)
{
    __shared__ float evf[16];
    const int row = blockIdx.x, tid = threadIdx.x;

    if (tid < 64) {
        float v[11];
        if (tid < 32) {
            const float* p = part + ((size_t)row * 32 + tid) * 8;
            float4 a = *(const float4*)p;
            float4 b = *(const float4*)(p + 4);
            float nrm = a.x;
            int bnn = tid >> 1;
            v[0] = nrm;
            v[1] = (bnn & 8) ? -nrm : nrm;
            v[2] = (bnn & 4) ? -nrm : nrm;
            v[3] = (bnn & 2) ? -nrm : nrm;
            v[4] = (bnn & 1) ? -nrm : nrm;
            v[5] = a.y; v[6] = a.z; v[7] = a.w;
            v[8] = b.x; v[9] = b.y; v[10] = b.z;
        } else {
#pragma unroll
            for (int k = 0; k < 11; ++k) v[k] = 0.f;
        }
#pragma unroll
        for (int m = 16; m; m >>= 1)
#pragma unroll
            for (int k = 0; k < 11; ++k) v[k] += __shfl_xor(v[k], m, 64);
        if (tid == 0) {
            float inv = 1.0f / v[0];
#pragma unroll
            for (int k = 0; k < 10; ++k) evf[k] = v[k + 1] * inv;
        }
    }
    __syncthreads();
    if (tid < PRED) {
        float o = b_out[tid];
#pragma unroll
        for (int k = 0; k < NQ; ++k) o = fmaf(W_out[tid * NQ + k], evf[k], o);
        out[(size_t)row * PRED + tid] = o;
    }
}

extern "C" void kernel_launch(void* const* d_in, const int* in_sizes, int n_in,
                              void* d_out, int out_size, void* d_ws, size_t ws_size,
                              hipStream_t stream) {
    const float* x     = (const float*)d_in[0];
    const float* W_in  = (const float*)d_in[1];
    const float* b_in  = (const float*)d_in[2];
    const float* qw    = (const float*)d_in[3];
    const float* W_out = (const float*)d_in[4];
    const float* b_out = (const float*)d_in[5];
    float* out = (float*)d_out;

    char* w = (char*)d_ws;
    const size_t MB = 1u << 20;
    ushort_t* xh    = (ushort_t*)w;               // 4 MB  f16 x
    ushort_t* Crt_r = (ushort_t*)(w + 4 * MB);    // 1 MB  [s][j]
    ushort_t* Crt_i = (ushort_t*)(w + 5 * MB);    // 1 MB
    float*    dr    = (float*)(w + 6 * MB);       // 4 KB
    float*    di    = dr + DIM;                   // 4 KB
    float*    part  = (float*)(w + 7 * MB);       // 4 MB

    convert_x_kernel<<<NROWS * SEQ / (256 * 8), 256, 0, stream>>>(x, xh);
    circuit_hybrid_kernel<<<SEQ + 1, 256, 0, stream>>>(W_in, b_in, qw, Crt_r, Crt_i, dr, di);
    dim3 g2(NROWS / GBM, DIM / GBNC);
    gemm_fused_kernel<<<g2, 256, 0, stream>>>(xh, Crt_r, Crt_i, dr, di, part);
    finalize_kernel<<<NROWS, 128, 0, stream>>>(part, W_out, b_out, out);
}

// Round 7
// 108.477 us; speedup vs baseline: 1.2674x; 1.0178x over previous
//
#include <hip/hip_runtime.h>
#include <math.h>

#define DIM 1024
#define NQ 10
#define NL 4
#define SEQ 512
#define NROWS 4096
#define PRED 96

typedef unsigned short ushort_t;
typedef unsigned int uint_t;
using half8   = __attribute__((ext_vector_type(8))) _Float16;
using float4v = __attribute__((ext_vector_type(4))) float;

__device__ inline ushort_t f2h(float f) { _Float16 h = (_Float16)f; return *(ushort_t*)&h; }
__device__ inline uint_t pkh(float a, float b) {
    _Float16 ha = (_Float16)a, hb = (_Float16)b;   // RTE v_cvt_f16_f32
    return (uint_t)(*(ushort_t*)&ha) | ((uint_t)(*(ushort_t*)&hb) << 16);
}

// ---------------------------------------------------------------------------
// Kernel 0 (FUSED): blocks 0..1023: x fp32 -> xh f16 (verbatim verified path).
//                   blocks 1024..1151: 64x64 LDS transpose W_in -> WiT[j][s].
// (Transpose is value-identical data movement; exonerated by R5's bisection.)
// ---------------------------------------------------------------------------
#define CVT_BLOCKS 1024
#define TRN_BLOCKS 128   // (DIM/64) * (SEQ/64) = 16*8

__global__ __launch_bounds__(256)
void convert_x_kernel(const float* __restrict__ x, ushort_t* __restrict__ xh,
                      const float* __restrict__ Wi, float* __restrict__ WiT)
{
    __shared__ float t[64][65];
    const int tid = threadIdx.x;
    const int bid = blockIdx.x;

    if (bid < CVT_BLOCKS) {
        int i = (bid * 256 + tid) * 8;
        float4 a = *(const float4*)(x + i);
        float4 b = *(const float4*)(x + i + 4);
        uint4 o;
        o.x = pkh(a.x, a.y); o.y = pkh(a.z, a.w);
        o.z = pkh(b.x, b.y); o.w = pkh(b.z, b.w);
        *(uint4*)(xh + i) = o;
    } else {
        const int b = bid - CVT_BLOCKS;        // 0..127
        const int s0 = (b & 15) * 64;          // 16 s-tiles over DIM
        const int j0 = (b >> 4) * 64;          // 8 j-tiles over SEQ
        {
            const int r = tid >> 2, cs = (tid & 3) * 16;
            const float* src = Wi + (size_t)(s0 + r) * SEQ + j0 + cs;
            float4 v0 = *(const float4*)(src);
            float4 v1 = *(const float4*)(src + 4);
            float4 v2 = *(const float4*)(src + 8);
            float4 v3 = *(const float4*)(src + 12);
            t[r][cs + 0] = v0.x; t[r][cs + 1] = v0.y; t[r][cs + 2] = v0.z; t[r][cs + 3] = v0.w;
            t[r][cs + 4] = v1.x; t[r][cs + 5] = v1.y; t[r][cs + 6] = v1.z; t[r][cs + 7] = v1.w;
            t[r][cs + 8] = v2.x; t[r][cs + 9] = v2.y; t[r][cs +10] = v2.z; t[r][cs +11] = v2.w;
            t[r][cs +12] = v3.x; t[r][cs +13] = v3.y; t[r][cs +14] = v3.z; t[r][cs +15] = v3.w;
        }
        __syncthreads();
        {
            const int jj = tid >> 2, ss = (tid & 3) * 16;
            float* dst = WiT + (size_t)(j0 + jj) * DIM + s0 + ss;
#pragma unroll
            for (int seg = 0; seg < 4; ++seg) {
                float4 o;
                o.x = t[ss + seg * 4 + 0][jj];
                o.y = t[ss + seg * 4 + 1][jj];
                o.z = t[ss + seg * 4 + 2][jj];
                o.w = t[ss + seg * 4 + 3][jj];
                *(float4*)(dst + seg * 4) = o;
            }
        }
    }
}

// ---------------------------------------------------------------------------
// Kernel 1: hybrid circuit (verbatim R2/R6-verified body), EXCEPT the state
// load reads WiT[j][s] as ONE coalesced float4 per thread.
// ---------------------------------------------------------------------------
__global__ __launch_bounds__(256)
void circuit_hybrid_kernel(const float* __restrict__ WiT, const float* __restrict__ b_in,
                           const float* __restrict__ qw,
                           ushort_t* __restrict__ Crt_r, ushort_t* __restrict__ Crt_i,
                           float* __restrict__ dr, float* __restrict__ di)
{
    __shared__ float gm[NL * NQ][8];
    __shared__ float bre[2][DIM];
    __shared__ float bim[2][DIM];

    const int tid = threadIdx.x;
    const int j = blockIdx.x;

    if (tid < NL * NQ) {
        float phi = qw[tid * 3 + 0], theta = qw[tid * 3 + 1], omega = qw[tid * 3 + 2];
        float ch = cosf(theta * 0.5f), sh = sinf(theta * 0.5f);
        float a = 0.5f * (phi + omega), b = 0.5f * (phi - omega);
        float ca = cosf(a), sa = sinf(a);
        float cb = cosf(b), sb = sinf(b);
        gm[tid][0] =  ch * ca;  gm[tid][1] = -ch * sa;   // m00
        gm[tid][2] = -sh * cb;  gm[tid][3] = -sh * sb;   // m01
        gm[tid][4] =  sh * cb;  gm[tid][5] = -sh * sb;   // m10
        gm[tid][6] =  ch * ca;  gm[tid][7] =  ch * sa;   // m11
    }

    // ---- load 4 states: s = tid*4 + r (coalesced from WiT) ----
    float2 st[4];
    if (j < SEQ) {
        float4 wv = *(const float4*)(WiT + (size_t)j * DIM + tid * 4);
        st[0] = make_float2(wv.x, 0.f);
        st[1] = make_float2(wv.y, 0.f);
        st[2] = make_float2(wv.z, 0.f);
        st[3] = make_float2(wv.w, 0.f);
    } else {
#pragma unroll
        for (int r = 0; r < 4; ++r)
            st[r] = make_float2(b_in[tid * 4 + r] + 1e-6f, 0.f);
    }
#pragma unroll
    for (int r = 0; r < 4; ++r) {
        bre[0][r * 256 + tid] = st[r].x;
        bim[0][r * 256 + tid] = st[r].y;
    }
    __syncthreads();
    int cur = 0;

    // ---- layer 0, wire 0 (bit 9) ----
    {
        const float* m = gm[0];
        const int hi = tid >> 7;
        float cAr = hi ? m[6] : m[0], cAi = hi ? m[7] : m[1];
        float cBr = hi ? m[4] : m[2], cBi = hi ? m[5] : m[3];
#pragma unroll
        for (int r = 0; r < 4; ++r) {
            float px = bre[cur][r * 256 + (tid ^ 128)];
            float py = bim[cur][r * 256 + (tid ^ 128)];
            float nx = cAr * st[r].x - cAi * st[r].y + cBr * px - cBi * py;
            float ny = cAr * st[r].y + cAi * st[r].x + cBr * py + cBi * px;
            st[r] = make_float2(nx, ny);
        }
    }

#pragma unroll
    for (int l = 0; l < NL; ++l) {
        // ---- wire 1 (bit 8): LDS round ----
        {
#pragma unroll
            for (int r = 0; r < 4; ++r) {
                bre[cur ^ 1][r * 256 + tid] = st[r].x;
                bim[cur ^ 1][r * 256 + tid] = st[r].y;
            }
            __syncthreads();
            cur ^= 1;
            const float* m = gm[l * NQ + 1];
            const int hi = (tid >> 6) & 1;
            float cAr = hi ? m[6] : m[0], cAi = hi ? m[7] : m[1];
            float cBr = hi ? m[4] : m[2], cBi = hi ? m[5] : m[3];
#pragma unroll
            for (int r = 0; r < 4; ++r) {
                float px = bre[cur][r * 256 + (tid ^ 64)];
                float py = bim[cur][r * 256 + (tid ^ 64)];
                float nx = cAr * st[r].x - cAi * st[r].y + cBr * px - cBi * py;
                float ny = cAr * st[r].y + cAi * st[r].x + cBr * py + cBi * px;
                st[r] = make_float2(nx, ny);
            }
        }
        // ---- wires 2..7: shuffles ----
#pragma unroll
        for (int w = 2; w < 8; ++w) {
            const float* m = gm[l * NQ + w];
            const int lb = 7 - w;
            const int hi = (tid >> lb) & 1;
            float cAr = hi ? m[6] : m[0], cAi = hi ? m[7] : m[1];
            float cBr = hi ? m[4] : m[2], cBi = hi ? m[5] : m[3];
            const int mask = 1 << lb;
#pragma unroll
            for (int r = 0; r < 4; ++r) {
                float px = __shfl_xor(st[r].x, mask, 64);
                float py = __shfl_xor(st[r].y, mask, 64);
                float nx = cAr * st[r].x - cAi * st[r].y + cBr * px - cBi * py;
                float ny = cAr * st[r].y + cAi * st[r].x + cBr * py + cBi * px;
                st[r] = make_float2(nx, ny);
            }
        }
        // ---- wire 8 (bit 1) ----
        {
            const float* m = gm[l * NQ + 8];
            float m00r = m[0], m00i = m[1], m01r = m[2], m01i = m[3];
            float m10r = m[4], m10i = m[5], m11r = m[6], m11i = m[7];
#pragma unroll
            for (int r0 = 0; r0 < 2; ++r0) {
                float2 a0 = st[r0], a1 = st[r0 + 2];
                st[r0].x     = m00r * a0.x - m00i * a0.y + m01r * a1.x - m01i * a1.y;
                st[r0].y     = m00r * a0.y + m00i * a0.x + m01r * a1.y + m01i * a1.x;
                st[r0 + 2].x = m10r * a0.x - m10i * a0.y + m11r * a1.x - m11i * a1.y;
                st[r0 + 2].y = m10r * a0.y + m10i * a0.x + m11r * a1.y + m11i * a1.x;
            }
        }
        // ---- wire 9 (bit 0) ----
        {
            const float* m = gm[l * NQ + 9];
            float m00r = m[0], m00i = m[1], m01r = m[2], m01i = m[3];
            float m10r = m[4], m10i = m[5], m11r = m[6], m11i = m[7];
#pragma unroll
            for (int r0 = 0; r0 < 4; r0 += 2) {
                float2 a0 = st[r0], a1 = st[r0 + 1];
                st[r0].x     = m00r * a0.x - m00i * a0.y + m01r * a1.x - m01i * a1.y;
                st[r0].y     = m00r * a0.y + m00i * a0.x + m01r * a1.y + m01i * a1.x;
                st[r0 + 1].x = m10r * a0.x - m10i * a0.y + m11r * a1.x - m11i * a1.y;
                st[r0 + 1].y = m10r * a0.y + m10i * a0.x + m11r * a1.y + m11i * a1.x;
            }
        }
        // ---- layer perm, fused with next layer's wire 0 ----
        {
#pragma unroll
            for (int r = 0; r < 4; ++r) {
                bre[cur ^ 1][r * 256 + tid] = st[r].x;
                bim[cur ^ 1][r * 256 + tid] = st[r].y;
            }
            __syncthreads();
            cur ^= 1;

            const int rr = l % (NQ - 1) + 1;
            int pbase = tid * 4;
            int p1 = 1, p2 = 2, p512 = 512;
#pragma unroll
            for (int c = 9; c >= 0; --c) {
                const int t = (c + rr) % NQ;
                pbase ^= ((pbase >> (9 - c)) & 1) << (9 - t);
                p1    ^= ((p1    >> (9 - c)) & 1) << (9 - t);
                p2    ^= ((p2    >> (9 - c)) & 1) << (9 - t);
                p512  ^= ((p512  >> (9 - c)) & 1) << (9 - t);
            }
            const int p3 = p1 ^ p2;
            int Ps[4] = {pbase, pbase ^ p1, pbase ^ p2, pbase ^ p3};

            if (l < NL - 1) {
                const float* m = gm[(l + 1) * NQ + 0];
                const int hi = tid >> 7;
                float cAr = hi ? m[6] : m[0], cAi = hi ? m[7] : m[1];
                float cBr = hi ? m[4] : m[2], cBi = hi ? m[5] : m[3];
#pragma unroll
                for (int r = 0; r < 4; ++r) {
                    int so = Ps[r];
                    int sp = so ^ p512;
                    int io = (so >> 2) | ((so & 3) << 8);
                    int ip = (sp >> 2) | ((sp & 3) << 8);
                    float ox = bre[cur][io], oy = bim[cur][io];
                    float px = bre[cur][ip], py = bim[cur][ip];
                    float nx = cAr * ox - cAi * oy + cBr * px - cBi * py;
                    float ny = cAr * oy + cAi * ox + cBr * py + cBi * px;
                    st[r] = make_float2(nx, ny);
                }
            } else {
#pragma unroll
                for (int r = 0; r < 4; ++r) {
                    int so = Ps[r];
                    int io = (so >> 2) | ((so & 3) << 8);
                    st[r] = make_float2(bre[cur][io], bim[cur][io]);
                }
            }
        }
    }

    // ---- store ----
    if (j < SEQ) {
#pragma unroll
        for (int r = 0; r < 4; ++r) {
            Crt_r[(size_t)(tid * 4 + r) * SEQ + j] = f2h(st[r].x);
            Crt_i[(size_t)(tid * 4 + r) * SEQ + j] = f2h(st[r].y);
        }
    } else {
#pragma unroll
        for (int r = 0; r < 4; ++r) {
            dr[tid * 4 + r] = st[r].x;
            di[tid * 4 + r] = st[r].y;
        }
    }
}

// ---------------------------------------------------------------------------
// Kernel 2: fused f16-MFMA GEMM + probs + signed partials.
// (Verbatim from the R6-verified 110.4us pipeline: GBK=64, no prefetch.)
// ---------------------------------------------------------------------------
#define GBM 128
#define GBNC 64
#define GBK 64
#define LDA 72   // half stride for LDS tiles (64 + 8 pad)
#define LDP 65   // float stride for probs tile

__global__ __launch_bounds__(256)
void gemm_fused_kernel(const ushort_t* __restrict__ xh,
                       const ushort_t* __restrict__ Crt_r, const ushort_t* __restrict__ Crt_i,
                       const float* __restrict__ dr, const float* __restrict__ di,
                       float* __restrict__ part)
{
    __shared__ __align__(16) char lds[(GBM + 2 * GBNC) * LDA * 2];
    ushort_t* Ash = (ushort_t*)lds;            // 128*72 halves
    ushort_t* Bsr = Ash + GBM * LDA;           // 64*72
    ushort_t* Bsi = Bsr + GBNC * LDA;          // 64*72
    float*    Ps  = (float*)lds;               // reused after K-loop
    __shared__ float drs[GBNC], dis[GBNC];

    const int tid = threadIdx.x;
    const int bm = blockIdx.x, bn = blockIdx.y;
    const int lane = tid & 63, wv = tid >> 6;
    const int n0 = bn * GBNC;

    if (tid < GBNC) { drs[tid] = dr[n0 + tid]; dis[tid] = di[n0 + tid]; }

    float4v accr[2][4], acci[2][4];
#pragma unroll
    for (int a = 0; a < 2; ++a)
#pragma unroll
        for (int b = 0; b < 4; ++b) { accr[a][b] = (float4v)0.f; acci[a][b] = (float4v)0.f; }

    // A staging: row sr (0..127), k offset ko (0 or 32); 32 halves/thread
    const int sr = tid >> 1, ko = (tid & 1) * 32;
    const ushort_t* xa = xh + (size_t)(bm * GBM + sr) * SEQ + ko;
    // B staging: threads 0-127 real, 128-255 imag; 32 halves each
    const int bsel = tid >> 7;
    const int nr = (tid & 127) >> 1;
    const int bko = (tid & 1) * 32;
    const ushort_t* bsrc = (bsel ? Crt_i : Crt_r) + (size_t)(n0 + nr) * SEQ + bko;
    ushort_t* bdst = (bsel ? Bsi : Bsr) + nr * LDA + bko;

    const int fm = lane & 15, kq = (lane >> 4) * 8;
    const int wrow = wv * 32;

    for (int k0 = 0; k0 < SEQ; k0 += GBK) {
        uint4 a0 = *(const uint4*)(xa + k0);
        uint4 a1 = *(const uint4*)(xa + k0 + 8);
        uint4 a2 = *(const uint4*)(xa + k0 + 16);
        uint4 a3 = *(const uint4*)(xa + k0 + 24);
        *(uint4*)(Ash + sr * LDA + ko)      = a0;
        *(uint4*)(Ash + sr * LDA + ko + 8)  = a1;
        *(uint4*)(Ash + sr * LDA + ko + 16) = a2;
        *(uint4*)(Ash + sr * LDA + ko + 24) = a3;
        uint4 b0 = *(const uint4*)(bsrc + k0);
        uint4 b1 = *(const uint4*)(bsrc + k0 + 8);
        uint4 b2 = *(const uint4*)(bsrc + k0 + 16);
        uint4 b3 = *(const uint4*)(bsrc + k0 + 24);
        *(uint4*)bdst        = b0;
        *(uint4*)(bdst + 8)  = b1;
        *(uint4*)(bdst + 16) = b2;
        *(uint4*)(bdst + 24) = b3;
        __syncthreads();

        // sub-tile 0 (k = k0 .. k0+31)
        {
            half8 ah0 = *(half8*)(Ash + (wrow + fm) * LDA + kq);
            half8 ah1 = *(half8*)(Ash + (wrow + 16 + fm) * LDA + kq);
#pragma unroll
            for (int nt = 0; nt < 4; ++nt) {
                half8 br = *(half8*)(Bsr + (nt * 16 + fm) * LDA + kq);
                half8 bi = *(half8*)(Bsi + (nt * 16 + fm) * LDA + kq);
                accr[0][nt] = __builtin_amdgcn_mfma_f32_16x16x32_f16(ah0, br, accr[0][nt], 0, 0, 0);
                accr[1][nt] = __builtin_amdgcn_mfma_f32_16x16x32_f16(ah1, br, accr[1][nt], 0, 0, 0);
                acci[0][nt] = __builtin_amdgcn_mfma_f32_16x16x32_f16(ah0, bi, acci[0][nt], 0, 0, 0);
                acci[1][nt] = __builtin_amdgcn_mfma_f32_16x16x32_f16(ah1, bi, acci[1][nt], 0, 0, 0);
            }
        }
        // sub-tile 1 (k = k0+32 .. k0+63)
        {
            half8 ah0 = *(half8*)(Ash + (wrow + fm) * LDA + 32 + kq);
            half8 ah1 = *(half8*)(Ash + (wrow + 16 + fm) * LDA + 32 + kq);
#pragma unroll
            for (int nt = 0; nt < 4; ++nt) {
                half8 br = *(half8*)(Bsr + (nt * 16 + fm) * LDA + 32 + kq);
                half8 bi = *(half8*)(Bsi + (nt * 16 + fm) * LDA + 32 + kq);
                accr[0][nt] = __builtin_amdgcn_mfma_f32_16x16x32_f16(ah0, br, accr[0][nt], 0, 0, 0);
                accr[1][nt] = __builtin_amdgcn_mfma_f32_16x16x32_f16(ah1, br, accr[1][nt], 0, 0, 0);
                acci[0][nt] = __builtin_amdgcn_mfma_f32_16x16x32_f16(ah0, bi, acci[0][nt], 0, 0, 0);
                acci[1][nt] = __builtin_amdgcn_mfma_f32_16x16x32_f16(ah1, bi, acci[1][nt], 0, 0, 0);
            }
        }
        __syncthreads();
    }

    // --- epilogue: p = zr^2 + zi^2 into LDS ---
    const int rq = (lane >> 4) * 4;
#pragma unroll
    for (int mt = 0; mt < 2; ++mt)
#pragma unroll
        for (int nt = 0; nt < 4; ++nt) {
            float drv = drs[nt * 16 + fm], div = dis[nt * 16 + fm];
#pragma unroll
            for (int reg = 0; reg < 4; ++reg) {
                int lrow = wrow + mt * 16 + rq + reg;
                float zr = accr[mt][nt][reg] + drv;
                float zi = acci[mt][nt][reg] + div;
                Ps[lrow * LDP + nt * 16 + fm] = zr * zr + zi * zi;
            }
        }
    __syncthreads();

    // --- signed partials over this block's 64 cols ---
    {
        const int row = tid >> 1, hh = tid & 1;
        const float* pr = Ps + row * LDP + hh * 32;
        float nrm = 0.f, e0 = 0.f, e1 = 0.f, e2 = 0.f, e3 = 0.f, e4 = 0.f, e5 = 0.f;
#pragma unroll
        for (int i = 0; i < 32; ++i) {
            float p = pr[i];
            int c = hh * 32 + i;
            nrm += p;
            e0 += ((c >> 5) & 1) ? -p : p;
            e1 += ((c >> 4) & 1) ? -p : p;
            e2 += ((c >> 3) & 1) ? -p : p;
            e3 += ((c >> 2) & 1) ? -p : p;
            e4 += ((c >> 1) & 1) ? -p : p;
            e5 += (c & 1) ? -p : p;
        }
        size_t base2 = ((size_t)(bm * GBM + row) * 32 + (bn * 2 + hh)) * 8;
        part[base2 + 0] = nrm;
        part[base2 + 1] = e0; part[base2 + 2] = e1; part[base2 + 3] = e2;
        part[base2 + 4] = e3; part[base2 + 5] = e4; part[base2 + 6] = e5;
    }
}

// ---------------------------------------------------------------------------
// Kernel 3: per-row wave-parallel combine of 32 partials + W_out epilogue.
// (Verbatim — verified.)
// ---------------------------------------------------------------------------
__global__ __launch_bounds__(128)
void finalize_kernel(const float* __restrict__ part, const float* __restrict__ W_out,
                     const float* __restrict__ b_out, float* __restrict__ out)
{
    __shared__ float evf[16];
    const int row = blockIdx.x, tid = threadIdx.x;

    if (tid < 64) {
        float v[11];
        if (tid < 32) {
            const float* p = part + ((size_t)row * 32 + tid) * 8;
            float4 a = *(const float4*)p;
            float4 b = *(const float4*)(p + 4);
            float nrm = a.x;
            int bnn = tid >> 1;
            v[0] = nrm;
            v[1] = (bnn & 8) ? -nrm : nrm;
            v[2] = (bnn & 4) ? -nrm : nrm;
            v[3] = (bnn & 2) ? -nrm : nrm;
            v[4] = (bnn & 1) ? -nrm : nrm;
            v[5] = a.y; v[6] = a.z; v[7] = a.w;
            v[8] = b.x; v[9] = b.y; v[10] = b.z;
        } else {
#pragma unroll
            for (int k = 0; k < 11; ++k) v[k] = 0.f;
        }
#pragma unroll
        for (int m = 16; m; m >>= 1)
#pragma unroll
            for (int k = 0; k < 11; ++k) v[k] += __shfl_xor(v[k], m, 64);
        if (tid == 0) {
            float inv = 1.0f / v[0];
#pragma unroll
            for (int k = 0; k < 10; ++k) evf[k] = v[k + 1] * inv;
        }
    }
    __syncthreads();
    if (tid < PRED) {
        float o = b_out[tid];
#pragma unroll
        for (int k = 0; k < NQ; ++k) o = fmaf(W_out[tid * NQ + k], evf[k], o);
        out[(size_t)row * PRED + tid] = o;
    }
}

extern "C" void kernel_launch(void* const* d_in, const int* in_sizes, int n_in,
                              void* d_out, int out_size, void* d_ws, size_t ws_size,
                              hipStream_t stream) {
    const float* x     = (const float*)d_in[0];
    const float* W_in  = (const float*)d_in[1];
    const float* b_in  = (const float*)d_in[2];
    const float* qw    = (const float*)d_in[3];
    const float* W_out = (const float*)d_in[4];
    const float* b_out = (const float*)d_in[5];
    float* out = (float*)d_out;

    char* w = (char*)d_ws;
    const size_t MB = 1u << 20;
    ushort_t* xh    = (ushort_t*)w;               // 4 MB  f16 x
    ushort_t* Crt_r = (ushort_t*)(w + 4 * MB);    // 1 MB  [s][j]
    ushort_t* Crt_i = (ushort_t*)(w + 5 * MB);    // 1 MB
    float*    dr    = (float*)(w + 6 * MB);       // 4 KB
    float*    di    = dr + DIM;                   // 4 KB
    float*    part  = (float*)(w + 7 * MB);       // 4 MB
    float*    WiT   = (float*)(w + 11 * MB);      // 2 MB  [j][s]

    convert_x_kernel<<<CVT_BLOCKS + TRN_BLOCKS, 256, 0, stream>>>(x, xh, W_in, WiT);
    circuit_hybrid_kernel<<<SEQ + 1, 256, 0, stream>>>(WiT, b_in, qw, Crt_r, Crt_i, dr, di);
    dim3 g2(NROWS / GBM, DIM / GBNC);
    gemm_fused_kernel<<<g2, 256, 0, stream>>>(xh, Crt_r, Crt_i, dr, di, part);
    finalize_kernel<<<NROWS, 128, 0, stream>>>(part, W_out, b_out, out);
}